// Round 9
// baseline (285.008 us; speedup 1.0000x reference)
//
#include <hip/hip_runtime.h>
#include <stdint.h>

// ---------- types / helpers ----------
typedef _Float16 h8 __attribute__((ext_vector_type(8)));
typedef _Float16 h4v __attribute__((ext_vector_type(4)));
typedef float f32x4 __attribute__((ext_vector_type(4)));

__device__ __forceinline__ float clampf(float x, float lo, float hi) {
    return fminf(fmaxf(x, lo), hi);
}
// async global->LDS, 16B per lane; lds dest must be wave-uniform base (+ lane*16 implied)
__device__ __forceinline__ void gload16(const _Float16* g, _Float16* l) {
    __builtin_amdgcn_global_load_lds(
        (const __attribute__((address_space(1))) unsigned int*)g,
        (__attribute__((address_space(3))) unsigned int*)l, 16, 0, 0);
}

// ---------- transpose f32 -> f16 (out[c][r] = in[r][c]) ----------
__global__ __launch_bounds__(256) void transpose_f2h(const float* __restrict__ in,
                                                     _Float16* __restrict__ out,
                                                     int rows, int cols) {
    __shared__ _Float16 tile[32][33];
    int bx = blockIdx.x * 32, by = blockIdx.y * 32;
    int tx = threadIdx.x & 31, ty = threadIdx.x >> 5;
    for (int i = ty; i < 32; i += 8)
        tile[i][tx] = (_Float16)in[(size_t)(by + i) * cols + bx + tx];
    __syncthreads();
    for (int i = ty; i < 32; i += 8)
        out[(size_t)(bx + i) * rows + by + tx] = tile[tx][i];
}

// ---------- LN1: f32 x -> f16 normed (one wave per 512-ch row) ----------
__global__ __launch_bounds__(256) void ln1_kernel(const float* __restrict__ x,
                                                  const float* __restrict__ scale,
                                                  _Float16* __restrict__ out) {
    int row = blockIdx.x * 4 + (threadIdx.x >> 6);
    int lane = threadIdx.x & 63;
    const float4* xp = (const float4*)(x + (size_t)row * 512 + lane * 8);
    float4 a = xp[0], b = xp[1];
    const float4* sp = (const float4*)(scale + lane * 8);
    float4 s0v = sp[0], s1v = sp[1];
    float f[8] = {a.x, a.y, a.z, a.w, b.x, b.y, b.z, b.w};
    float sc[8] = {s0v.x, s0v.y, s0v.z, s0v.w, s1v.x, s1v.y, s1v.z, s1v.w};
    float s = 0.f, ss = 0.f;
#pragma unroll
    for (int j = 0; j < 8; j++) { s += f[j]; ss += f[j] * f[j]; }
#pragma unroll
    for (int off = 1; off < 64; off <<= 1) { s += __shfl_xor(s, off); ss += __shfl_xor(ss, off); }
    float mean = s * (1.f / 512.f);
    float var  = ss * (1.f / 512.f) - mean * mean;
    float rs   = rsqrtf(fmaxf(var, 0.f) + 1e-5f);
    union { uint4 u; _Float16 h[8]; } ov;
#pragma unroll
    for (int j = 0; j < 8; j++) ov.h[j] = (_Float16)((f[j] - mean) * rs * sc[j]);
    *(uint4*)(out + (size_t)row * 512 + lane * 8) = ov.u;
}

// ---------- fused kv GEMM + exp + S + ctx (no kv materialization) ----------
// Block = one (batch bl, head h, n-quarter ns): 256 n-rows x 128 c (64 k + 64 v rows
// of the kv half of wqkvT). Swapped mfma -> acc = D[c][n] in registers.
// Epilogue: k-waves exp in-reg; 4 phases {owner wave-pair writes its 64-n chunk to
// T[128][72] in LDS; all 8 waves accumulate ctx partial via MFMA over K=64};
// S from the f16-rounded values ctx consumes. part2[ns][bh][d][e] f32.
__global__ __launch_bounds__(512) void gemm_kvctx(const _Float16* __restrict__ A,
                                                  const _Float16* __restrict__ BT,   // kv half
                                                  float* __restrict__ part2,
                                                  float* __restrict__ Sbuf) {
    __shared__ __attribute__((aligned(16))) char smem[24576];
    _Float16* Ws = (_Float16*)smem;            // [128][32]  8 KB (rows 0..63 k, 64..127 v)
    _Float16* Ns = (_Float16*)(smem + 8192);   // [256][32] 16 KB
    _Float16* T  = (_Float16*)smem;            // [128][72] overlay, 18432 B (144B rows)
    int t = threadIdx.x, w = t >> 6, lane = t & 63;
    int lm = lane & 15, q4 = lane >> 4;
    int ns = blockIdx.x, bh = blockIdx.y;
    int bl = bh >> 3, h = bh & 7;
    int nr0 = bl * 1024 + ns * 256;
    int wc = (w & 1) * 64, wn = (w >> 1) * 64;
    f32x4 acc[4][4];                           // [ci][nj]: c = wc+ci*16+lm, n = wn+nj*16+q4*4+r
#pragma unroll
    for (int i = 0; i < 4; i++)
#pragma unroll
        for (int j = 0; j < 4; j++) acc[i][j] = (f32x4){0.f, 0.f, 0.f, 0.f};

    int sr = t >> 2, sc = (t & 3) * 8;         // sr 0..127
    int grow = (sr < 64) ? (h * 64 + sr) : (512 + h * 64 + (sr - 64));
    const _Float16* Wg = BT + (size_t)grow * 512 + sc;
    const _Float16* Ng = A + (size_t)(nr0 + sr) * 512 + sc;
    _Float16* WsW = Ws + w * 512;              // wave-uniform dests (lane*16B implied)

    for (int k0 = 0; k0 < 512; k0 += 32) {
        gload16(Wg + k0, WsW);
#pragma unroll
        for (int j = 0; j < 2; j++)
            gload16(Ng + (size_t)j * 128 * 512 + k0, Ns + j * 4096 + w * 512);
        __syncthreads();
        h8 wf[4], nf[4];
#pragma unroll
        for (int i = 0; i < 4; i++) wf[i] = *(const h8*)(Ws + (wc + i * 16 + lm) * 32 + q4 * 8);
#pragma unroll
        for (int i = 0; i < 4; i++) nf[i] = *(const h8*)(Ns + (wn + i * 16 + lm) * 32 + q4 * 8);
#pragma unroll
        for (int ci = 0; ci < 4; ci++)
#pragma unroll
            for (int nj = 0; nj < 4; nj++)
                acc[ci][nj] = __builtin_amdgcn_mfma_f32_16x16x32_f16(nf[nj], wf[ci], acc[ci][nj], 0, 0, 0);
        __syncthreads();
    }
    // pre-pass: k-waves exponentiate in registers (parallel, no barrier needed)
    if ((w & 1) == 0) {
#pragma unroll
        for (int ci = 0; ci < 4; ci++)
#pragma unroll
            for (int nj = 0; nj < 4; nj++) {
                f32x4 v = acc[ci][nj];
#pragma unroll
                for (int r = 0; r < 4; r++) v[r] = __expf(clampf(v[r], -30.f, 30.f));
                acc[ci][nj] = v;
            }
    }
    int myChunk = w >> 1;                      // 64-n chunk this wave holds (0..3)
    int wd = (w & 3) * 16, we = (w >> 2) * 32; // ctx roles: d-tile, e-half
    f32x4 acc2[2];
    acc2[0] = (f32x4){0.f, 0.f, 0.f, 0.f};
    acc2[1] = (f32x4){0.f, 0.f, 0.f, 0.f};
    float ssum[4] = {0.f, 0.f, 0.f, 0.f};

#pragma unroll
    for (int j = 0; j < 4; j++) {
        if (myChunk == j) {                    // wave pair 2j (k), 2j+1 (v) writes T
            int rbase = (w & 1) * 64;
#pragma unroll
            for (int ci = 0; ci < 4; ci++) {
                float ss = 0.f;
#pragma unroll
                for (int nj = 0; nj < 4; nj++) {
                    f32x4 v = acc[ci][nj];
                    h4v o;
#pragma unroll
                    for (int r = 0; r < 4; r++) {
                        _Float16 e = (_Float16)v[r];
                        o[r] = e;
                        ss += (float)e;        // f16-rounded value ctx consumes
                    }
                    *(h4v*)(T + (rbase + ci * 16 + lm) * 72 + nj * 16 + q4 * 4) = o;
                }
                ssum[ci] = ss;                 // only meaningful for k-waves
            }
        }
        __syncthreads();                       // T chunk ready
#pragma unroll
        for (int ks = 0; ks < 2; ks++) {
            h8 af = *(const h8*)(T + (wd + lm) * 72 + ks * 32 + q4 * 8);
#pragma unroll
            for (int nt = 0; nt < 2; nt++) {
                h8 bf = *(const h8*)(T + (64 + we + nt * 16 + lm) * 72 + ks * 32 + q4 * 8);
                acc2[nt] = __builtin_amdgcn_mfma_f32_16x16x32_f16(bf, af, acc2[nt], 0, 0, 0);
            }
        }
        __syncthreads();                       // all ctx reads done before next chunk write
    }
    // S atomics: k-waves, d = ci*16+lm; q4 group covers the wave's 64 n
    if ((w & 1) == 0) {
#pragma unroll
        for (int ci = 0; ci < 4; ci++) {
            float s2 = ssum[ci];
            s2 += __shfl_xor(s2, 16);
            s2 += __shfl_xor(s2, 32);
            if (q4 == 0) atomicAdd(&Sbuf[bh * 64 + ci * 16 + lm], s2);
        }
    }
    float* dst = part2 + ((size_t)ns * 256 + bh) * 4096 + (wd + lm) * 64 + we;
#pragma unroll
    for (int nt = 0; nt < 2; nt++)
        *(f32x4*)(dst + nt * 16 + q4 * 4) = acc2[nt];
}

// ---------- fused q GEMM + per-head softmax + PV ----------
// A = normed, BT = wqkvT q-rows. Block: 128 rows x 128 cols = 2 complete heads.
// Wave's 64 cols = one head -> softmax sum fully in-wave (shfl_xor 16,32).
// PV: attn[n][h*64+e] = sum_d qn[n][d] * csT[e][d], K=64 MFMA from LDS tiles.
__global__ __launch_bounds__(256) void gemm_qattn(const _Float16* __restrict__ A,
                                                  const _Float16* __restrict__ BT,
                                                  const float* __restrict__ part,
                                                  const float* __restrict__ Sbuf,
                                                  _Float16* __restrict__ attn) {
    // smem: As/Bs (16 KB) during K-loop; then qn[128][132] (33792 B) + csT[2][64][68] (17408 B)
    __shared__ __attribute__((aligned(16))) char smem[33792 + 17408];
    _Float16* As  = (_Float16*)smem;
    _Float16* Bs  = (_Float16*)(smem + 8192);
    _Float16* qn  = (_Float16*)smem;             // [128][132]
    _Float16* csT = (_Float16*)(smem + 33792);   // [2][64][68]
    int t = threadIdx.x, w = t >> 6, lane = t & 63;
    int lm = lane & 15, q4 = lane >> 4;
    int m0 = blockIdx.y * 128, n0 = blockIdx.x * 128;
    int wm = (w & 1) * 64, wn = (w >> 1) * 64;
    f32x4 acc[4][4];
#pragma unroll
    for (int i = 0; i < 4; i++)
#pragma unroll
        for (int j = 0; j < 4; j++) acc[i][j] = (f32x4){0.f, 0.f, 0.f, 0.f};

    int sr = t >> 2, sc = (t & 3) * 8;
    const _Float16* Ag = A + (size_t)(m0 + sr) * 512 + sc;
    const _Float16* Bg = BT + (size_t)(n0 + sr) * 512 + sc;
    _Float16* AsW = As + w * 512;
    _Float16* BsW = Bs + w * 512;

    for (int k0 = 0; k0 < 512; k0 += 32) {
        gload16(Ag + k0, AsW);
        gload16(Ag + (size_t)64 * 512 + k0, AsW + 64 * 32);
        gload16(Bg + k0, BsW);
        gload16(Bg + (size_t)64 * 512 + k0, BsW + 64 * 32);
        __syncthreads();
        h8 af[4], bf[4];
#pragma unroll
        for (int i = 0; i < 4; i++) af[i] = *(const h8*)(As + (wm + i * 16 + lm) * 32 + q4 * 8);
#pragma unroll
        for (int i = 0; i < 4; i++) bf[i] = *(const h8*)(Bs + (wn + i * 16 + lm) * 32 + q4 * 8);
#pragma unroll
        for (int mi = 0; mi < 4; mi++)
#pragma unroll
            for (int ni = 0; ni < 4; ni++)
                acc[mi][ni] = __builtin_amdgcn_mfma_f32_16x16x32_f16(bf[ni], af[mi], acc[mi][ni], 0, 0, 0);
        __syncthreads();
    }
    // per-row softmax over this wave's head (64 cols): exp in-place, row sums via shfl over q4
    float rws[4];
#pragma unroll
    for (int mi = 0; mi < 4; mi++) {
        float s = 0.f;
#pragma unroll
        for (int ni = 0; ni < 4; ni++) {
            f32x4 e;
#pragma unroll
            for (int r = 0; r < 4; r++) {
                e[r] = __expf(clampf(acc[mi][ni][r], -30.f, 30.f));
                s += e[r];
            }
            acc[mi][ni] = e;
        }
        s += __shfl_xor(s, 16);
        s += __shfl_xor(s, 32);
        rws[mi] = 1.f / (s * 8.f);           // softmax / sqrt(64)
    }
    // write qn tile (f16) to LDS (overlays As/Bs; safe after final K-loop barrier)
#pragma unroll
    for (int mi = 0; mi < 4; mi++) {
        int row = wm + mi * 16 + lm;
        float r = rws[mi];
#pragma unroll
        for (int ni = 0; ni < 4; ni++) {
            int col0 = wn + ni * 16 + q4 * 4;
            h4v o;
#pragma unroll
            for (int j = 0; j < 4; j++) o[j] = (_Float16)(acc[mi][ni][j] * r);
            *(h4v*)(qn + row * 132 + col0) = o;
        }
    }
    // stage csT[hh][e][d] = (sum_ns part2[ns])[bh][d][e] * invS[d]  (f16, B^T layout)
    int bl = m0 >> 10;
    int head0 = n0 >> 6;
#pragma unroll
    for (int hh2 = 0; hh2 < 2; hh2++) {
        int bh = bl * 8 + head0 + hh2;
        const f32x4* p0 = (const f32x4*)(part + (size_t)bh * 4096);
        const f32x4* p1 = (const f32x4*)(part + (size_t)(256 + bh) * 4096);
        const f32x4* p2 = (const f32x4*)(part + (size_t)(512 + bh) * 4096);
        const f32x4* p3 = (const f32x4*)(part + (size_t)(768 + bh) * 4096);
        for (int i = t; i < 1024; i += 256) {
            f32x4 v = p0[i] + p1[i] + p2[i] + p3[i];
            int d = i >> 4, e0 = (i & 15) * 4;
            float is = 1.f / Sbuf[bh * 64 + d];
#pragma unroll
            for (int j = 0; j < 4; j++)
                csT[hh2 * 64 * 68 + (e0 + j) * 68 + d] = (_Float16)(v[j] * is);
        }
    }
    __syncthreads();
    // PV: per wave: rows wm..+63 of its head hh = w>>1, e-cols wn&63 (== output cols)
    int hh = w >> 1;
    f32x4 acc2[4][4];
#pragma unroll
    for (int i = 0; i < 4; i++)
#pragma unroll
        for (int j = 0; j < 4; j++) acc2[i][j] = (f32x4){0.f, 0.f, 0.f, 0.f};
#pragma unroll
    for (int kc = 0; kc < 2; kc++) {
        h8 af[4], bf[4];
#pragma unroll
        for (int mi = 0; mi < 4; mi++) {
            const _Float16* p = qn + (wm + mi * 16 + lm) * 132 + hh * 64 + kc * 32 + q4 * 8;
            h4v lo = *(const h4v*)p;
            h4v hi = *(const h4v*)(p + 4);
            h8 a;
#pragma unroll
            for (int j = 0; j < 4; j++) { a[j] = lo[j]; a[4 + j] = hi[j]; }
            af[mi] = a;
        }
#pragma unroll
        for (int ni = 0; ni < 4; ni++) {
            const _Float16* p = csT + hh * 64 * 68 + (ni * 16 + lm) * 68 + kc * 32 + q4 * 8;
            h4v lo = *(const h4v*)p;
            h4v hi = *(const h4v*)(p + 4);
            h8 b;
#pragma unroll
            for (int j = 0; j < 4; j++) { b[j] = lo[j]; b[4 + j] = hi[j]; }
            bf[ni] = b;
        }
#pragma unroll
        for (int mi = 0; mi < 4; mi++)
#pragma unroll
            for (int ni = 0; ni < 4; ni++)
                acc2[mi][ni] = __builtin_amdgcn_mfma_f32_16x16x32_f16(bf[ni], af[mi], acc2[mi][ni], 0, 0, 0);
    }
#pragma unroll
    for (int mi = 0; mi < 4; mi++) {
        int row = m0 + wm + mi * 16 + lm;
#pragma unroll
        for (int ni = 0; ni < 4; ni++) {
            int col0 = n0 + wn + ni * 16 + q4 * 4;   // == h*64 + e directly
            h4v o;
#pragma unroll
            for (int r = 0; r < 4; r++) o[r] = (_Float16)acc2[mi][ni][r];
            *(h4v*)(attn + (size_t)row * 512 + col0) = o;
        }
    }
}

// ---------- fused projection GEMM + bias + LN2 + residual (64-row blocks) ----------
// out[m0+row][:] = LN( attn[row] . woutT^T / 1024 + b_out ) * ln2_scale + x[row]
// 512 threads = 8 waves, each wave -> 64-col slice; 64 rows/block (full rows -> LN in-block).
__global__ __launch_bounds__(512) void gemm_projln2(const _Float16* __restrict__ A,
                                                    const _Float16* __restrict__ BT,
                                                    const float* __restrict__ bias,
                                                    const float* __restrict__ x,
                                                    const float* __restrict__ scale,
                                                    float* __restrict__ out) {
    __shared__ __attribute__((aligned(16))) _Float16 As[64 * 32];    //  4 KB
    __shared__ __attribute__((aligned(16))) _Float16 Bs[512 * 32];   // 32 KB
    __shared__ float rs_sum[64][8];                                  //  2 KB
    __shared__ float rs_ssq[64][8];                                  //  2 KB
    int t = threadIdx.x, w = t >> 6, lane = t & 63;
    int lm = lane & 15, q4 = lane >> 4;
    int m0 = blockIdx.x * 64;
    f32x4 acc[4][4];   // [mi][ni]: row = m0+mi*16+lm, col = w*64+ni*16+q4*4+r
#pragma unroll
    for (int i = 0; i < 4; i++)
#pragma unroll
        for (int j = 0; j < 4; j++) acc[i][j] = (f32x4){0.f, 0.f, 0.f, 0.f};

    int sr = t >> 2, sc = (t & 3) * 8;     // B staging: rows 0..127 per call
    const _Float16* Ag = A + (size_t)(m0 + (w & 3) * 16 + (lane >> 2)) * 512 + (lane & 3) * 8;
    const _Float16* Bg = BT + (size_t)sr * 512 + sc;
    _Float16* AsW = As + (w & 3) * 512;    // wave-uniform (lane*16B implied)

    for (int k0 = 0; k0 < 512; k0 += 32) {
        if (w < 4) gload16(Ag + k0, AsW);  // waves 0-3 stage 16 rows each
#pragma unroll
        for (int j = 0; j < 4; j++)
            gload16(Bg + (size_t)j * 128 * 512 + k0, Bs + j * 4096 + w * 512);
        __syncthreads();
        h8 af[4], bf[4];
#pragma unroll
        for (int i = 0; i < 4; i++) af[i] = *(const h8*)(As + (i * 16 + lm) * 32 + q4 * 8);
#pragma unroll
        for (int i = 0; i < 4; i++) bf[i] = *(const h8*)(Bs + (w * 64 + i * 16 + lm) * 32 + q4 * 8);
#pragma unroll
        for (int mi = 0; mi < 4; mi++)
#pragma unroll
            for (int ni = 0; ni < 4; ni++)
                acc[mi][ni] = __builtin_amdgcn_mfma_f32_16x16x32_f16(bf[ni], af[mi], acc[mi][ni], 0, 0, 0);
        __syncthreads();
    }
    // scale + bias; per-(row,wave) partials over this wave's 64 cols
    const float os = 1.f / 1024.f;
#pragma unroll
    for (int mi = 0; mi < 4; mi++) {
        float s = 0.f, ss = 0.f;
#pragma unroll
        for (int ni = 0; ni < 4; ni++) {
            float4 b4 = *(const float4*)(bias + w * 64 + ni * 16 + q4 * 4);
            const float* bp = &b4.x;
#pragma unroll
            for (int r = 0; r < 4; r++) {
                float v = acc[mi][ni][r] * os + bp[r];
                acc[mi][ni][r] = v;
                s += v; ss += v * v;
            }
        }
        s  += __shfl_xor(s, 16);  s  += __shfl_xor(s, 32);
        ss += __shfl_xor(ss, 16); ss += __shfl_xor(ss, 32);
        if (q4 == 0) {
            rs_sum[mi * 16 + lm][w] = s;
            rs_ssq[mi * 16 + lm][w] = ss;
        }
    }
    __syncthreads();
#pragma unroll
    for (int mi = 0; mi < 4; mi++) {
        int r64 = mi * 16 + lm;
        float s = 0.f, ss = 0.f;
#pragma unroll
        for (int k = 0; k < 8; k++) { s += rs_sum[r64][k]; ss += rs_ssq[r64][k]; }
        float mean = s * (1.f / 512.f);
        float var  = ss * (1.f / 512.f) - mean * mean;
        float rstd = rsqrtf(fmaxf(var, 0.f) + 1e-5f);
        int row = m0 + r64;
#pragma unroll
        for (int ni = 0; ni < 4; ni++) {
            int col0 = w * 64 + ni * 16 + q4 * 4;
            float4 sc4 = *(const float4*)(scale + col0);
            float4 x4  = *(const float4*)(x + (size_t)row * 512 + col0);
            const float* scp = &sc4.x; const float* xp = &x4.x;
            float4 o;
            float* op = &o.x;
#pragma unroll
            for (int r = 0; r < 4; r++)
                op[r] = (acc[mi][ni][r] - mean) * rstd * scp[r] + xp[r];
            *(float4*)(out + (size_t)row * 512 + col0) = o;
        }
    }
}

// ---------- launch ----------
extern "C" void kernel_launch(void* const* d_in, const int* in_sizes, int n_in,
                              void* d_out, int out_size, void* d_ws, size_t ws_size,
                              hipStream_t stream) {
    const float* x    = (const float*)d_in[0];
    const float* ln1s = (const float*)d_in[1];
    const float* wqkv = (const float*)d_in[2];
    const float* wout = (const float*)d_in[3];
    const float* bout = (const float*)d_in[4];
    const float* ln2s = (const float*)d_in[5];
    float* out = (float*)d_out;

    char* ws = (char*)d_ws;
    // ws layout (unchanged footprint):
    _Float16* wqkvT  = (_Float16*)(ws);                     // 1,572,864
    _Float16* woutT  = (_Float16*)(ws + 1572864);           //   524,288
    float*    Sbuf   = (float*)(ws + 6291456);              // [256][64] f32 : 64 KiB
    _Float16* normed = (_Float16*)(ws + 6356992);           // [32768][512] f16 : 32 MiB
    _Float16* attnF  = (_Float16*)(ws + 39911424);          // [32768][512] f16 : 32 MiB
    // d_out (64 MiB) is scratch until gemm_projln2: part2 dead after qattn.
    float* part2 = (float*)d_out;                           // [4][256][64][64] f32 : 16 MiB

    transpose_f2h<<<dim3(48, 16), 256, 0, stream>>>(wqkv, wqkvT, 512, 1536);
    transpose_f2h<<<dim3(16, 16), 256, 0, stream>>>(wout, woutT, 512, 512);
    ln1_kernel<<<8192, 256, 0, stream>>>(x, ln1s, normed);
    hipMemsetAsync(Sbuf, 0, 65536, stream);

    // kv GEMM + exp + S + ctx fused (no ekT/vT materialization); 1024 blocks = 4/CU
    gemm_kvctx<<<dim3(4, 256), 512, 0, stream>>>(normed, wqkvT + 512 * 512, part2, Sbuf);
    // q = normed . w_qkv[:, 0:512] with fused softmax + PV (all batches)
    gemm_qattn<<<dim3(4, 256), 256, 0, stream>>>(normed, wqkvT, part2, Sbuf, attnF);
    // out = LN(attn . w_out^T / 1024 + b_out) * ln2_scale + x
    gemm_projln2<<<512, 512, 0, stream>>>(attnF, woutT, bout, x, ln2s, out);
}

// Round 10
// 275.596 us; speedup vs baseline: 1.0342x; 1.0342x over previous
//
#include <hip/hip_runtime.h>
#include <stdint.h>

// ---------- types / helpers ----------
typedef _Float16 h8 __attribute__((ext_vector_type(8)));
typedef _Float16 h4v __attribute__((ext_vector_type(4)));
typedef float f32x4 __attribute__((ext_vector_type(4)));

__device__ __forceinline__ float clampf(float x, float lo, float hi) {
    return fminf(fmaxf(x, lo), hi);
}
// async global->LDS, 16B per lane; lds dest must be wave-uniform base (+ lane*16 implied)
__device__ __forceinline__ void gload16(const _Float16* g, _Float16* l) {
    __builtin_amdgcn_global_load_lds(
        (const __attribute__((address_space(1))) unsigned int*)g,
        (__attribute__((address_space(3))) unsigned int*)l, 16, 0, 0);
}

// ---------- transpose f32 -> f16 (out[c][r] = in[r][c]) ----------
__global__ __launch_bounds__(256) void transpose_f2h(const float* __restrict__ in,
                                                     _Float16* __restrict__ out,
                                                     int rows, int cols) {
    __shared__ _Float16 tile[32][33];
    int bx = blockIdx.x * 32, by = blockIdx.y * 32;
    int tx = threadIdx.x & 31, ty = threadIdx.x >> 5;
    for (int i = ty; i < 32; i += 8)
        tile[i][tx] = (_Float16)in[(size_t)(by + i) * cols + bx + tx];
    __syncthreads();
    for (int i = ty; i < 32; i += 8)
        out[(size_t)(bx + i) * rows + by + tx] = tile[tx][i];
}

// ---------- LN1: f32 x -> f16 normed (one wave per 512-ch row) ----------
__global__ __launch_bounds__(256) void ln1_kernel(const float* __restrict__ x,
                                                  const float* __restrict__ scale,
                                                  _Float16* __restrict__ out) {
    int row = blockIdx.x * 4 + (threadIdx.x >> 6);
    int lane = threadIdx.x & 63;
    const float4* xp = (const float4*)(x + (size_t)row * 512 + lane * 8);
    float4 a = xp[0], b = xp[1];
    const float4* sp = (const float4*)(scale + lane * 8);
    float4 s0v = sp[0], s1v = sp[1];
    float f[8] = {a.x, a.y, a.z, a.w, b.x, b.y, b.z, b.w};
    float sc[8] = {s0v.x, s0v.y, s0v.z, s0v.w, s1v.x, s1v.y, s1v.z, s1v.w};
    float s = 0.f, ss = 0.f;
#pragma unroll
    for (int j = 0; j < 8; j++) { s += f[j]; ss += f[j] * f[j]; }
#pragma unroll
    for (int off = 1; off < 64; off <<= 1) { s += __shfl_xor(s, off); ss += __shfl_xor(ss, off); }
    float mean = s * (1.f / 512.f);
    float var  = ss * (1.f / 512.f) - mean * mean;
    float rs   = rsqrtf(fmaxf(var, 0.f) + 1e-5f);
    union { uint4 u; _Float16 h[8]; } ov;
#pragma unroll
    for (int j = 0; j < 8; j++) ov.h[j] = (_Float16)((f[j] - mean) * rs * sc[j]);
    *(uint4*)(out + (size_t)row * 512 + lane * 8) = ov.u;
}

// ---------- fused kv GEMM + exp + S + ctx (no kv materialization) — R8 proven version ----------
// Block = one (batch bl, head h, n-half ns): 512 n-rows x 128 c (64 k-rows + 64 v-rows
// of the kv half of wqkvT). Swapped mfma -> acc = D[c][n] in registers.
// Epilogue: k-waves exp in-reg; 4 n-chunk phases {owner pair writes T[128][136] in LDS;
// all waves accumulate ctx partial via MFMA over K=128}; S from f16-rounded values.
// part2[ns][bh][d][e] f32 (summed by qattn).
__global__ __launch_bounds__(512) void gemm_kvctx(const _Float16* __restrict__ A,
                                                  const _Float16* __restrict__ BT,   // kv half
                                                  float* __restrict__ part2,
                                                  float* __restrict__ Sbuf) {
    __shared__ __attribute__((aligned(16))) char smem[40960];
    _Float16* Ws = (_Float16*)smem;            // [128][32]  8 KB (rows 0..63 k, 64..127 v)
    _Float16* Ns = (_Float16*)(smem + 8192);   // [512][32] 32 KB
    _Float16* T  = (_Float16*)smem;            // [128][136] overlay, 34816 B (16B-aligned rows)
    int t = threadIdx.x, w = t >> 6, lane = t & 63;
    int lm = lane & 15, q4 = lane >> 4;
    int ns = blockIdx.x, bh = blockIdx.y;
    int bl = bh >> 3, h = bh & 7;
    int nr0 = bl * 1024 + ns * 512;
    int wc = (w & 1) * 64, wn = (w >> 1) * 128;
    f32x4 acc[4][8];                           // [ci][nj]: c = wc+ci*16+lm, n = wn+nj*16+q4*4+r
#pragma unroll
    for (int i = 0; i < 4; i++)
#pragma unroll
        for (int j = 0; j < 8; j++) acc[i][j] = (f32x4){0.f, 0.f, 0.f, 0.f};

    int sr = t >> 2, sc = (t & 3) * 8;         // sr 0..127
    int grow = (sr < 64) ? (h * 64 + sr) : (512 + h * 64 + (sr - 64));
    const _Float16* Wg = BT + (size_t)grow * 512 + sc;
    const _Float16* Ng = A + (size_t)(nr0 + sr) * 512 + sc;
    _Float16* WsW = Ws + w * 512;              // wave-uniform dests (lane*16B implied)

    for (int k0 = 0; k0 < 512; k0 += 32) {
        gload16(Wg + k0, WsW);
#pragma unroll
        for (int j = 0; j < 4; j++)
            gload16(Ng + (size_t)j * 128 * 512 + k0, Ns + j * 4096 + w * 512);
        __syncthreads();
        h8 wf[4], nf[8];
#pragma unroll
        for (int i = 0; i < 4; i++) wf[i] = *(const h8*)(Ws + (wc + i * 16 + lm) * 32 + q4 * 8);
#pragma unroll
        for (int i = 0; i < 8; i++) nf[i] = *(const h8*)(Ns + (wn + i * 16 + lm) * 32 + q4 * 8);
#pragma unroll
        for (int ci = 0; ci < 4; ci++)
#pragma unroll
            for (int nj = 0; nj < 8; nj++)
                acc[ci][nj] = __builtin_amdgcn_mfma_f32_16x16x32_f16(nf[nj], wf[ci], acc[ci][nj], 0, 0, 0);
        __syncthreads();
    }
    // pre-pass: k-waves exponentiate in registers (parallel, no barrier needed)
    if ((w & 1) == 0) {
#pragma unroll
        for (int ci = 0; ci < 4; ci++)
#pragma unroll
            for (int nj = 0; nj < 8; nj++) {
                f32x4 v = acc[ci][nj];
#pragma unroll
                for (int r = 0; r < 4; r++) v[r] = __expf(clampf(v[r], -30.f, 30.f));
                acc[ci][nj] = v;
            }
    }
    int myChunk = w >> 1;                      // n-chunk this wave holds (0..3)
    int wd = (w & 3) * 16, we = (w >> 2) * 32; // ctx roles: d-tile, e-half
    f32x4 acc2[2];
    acc2[0] = (f32x4){0.f, 0.f, 0.f, 0.f};
    acc2[1] = (f32x4){0.f, 0.f, 0.f, 0.f};
    float ssum[4] = {0.f, 0.f, 0.f, 0.f};

#pragma unroll
    for (int j = 0; j < 4; j++) {
        if (myChunk == j) {                    // wave pair 2j (k), 2j+1 (v) writes T
            int rbase = (w & 1) * 64;
#pragma unroll
            for (int ci = 0; ci < 4; ci++) {
                float ss = 0.f;
#pragma unroll
                for (int nj = 0; nj < 8; nj++) {
                    f32x4 v = acc[ci][nj];
                    h4v o;
#pragma unroll
                    for (int r = 0; r < 4; r++) {
                        _Float16 e = (_Float16)v[r];
                        o[r] = e;
                        ss += (float)e;        // f16-rounded value ctx consumes
                    }
                    *(h4v*)(T + (rbase + ci * 16 + lm) * 136 + nj * 16 + q4 * 4) = o;
                }
                ssum[ci] = ss;                 // only meaningful for k-waves
            }
        }
        __syncthreads();                       // T chunk ready
#pragma unroll
        for (int ks = 0; ks < 4; ks++) {
            h8 af = *(const h8*)(T + (wd + lm) * 136 + ks * 32 + q4 * 8);
#pragma unroll
            for (int nt = 0; nt < 2; nt++) {
                h8 bf = *(const h8*)(T + (64 + we + nt * 16 + lm) * 136 + ks * 32 + q4 * 8);
                acc2[nt] = __builtin_amdgcn_mfma_f32_16x16x32_f16(bf, af, acc2[nt], 0, 0, 0);
            }
        }
        __syncthreads();                       // all ctx reads done before next chunk write
    }
    // S atomics: k-waves, d = ci*16+lm; q4 group covers the wave's 128 n
    if ((w & 1) == 0) {
#pragma unroll
        for (int ci = 0; ci < 4; ci++) {
            float s2 = ssum[ci];
            s2 += __shfl_xor(s2, 16);
            s2 += __shfl_xor(s2, 32);
            if (q4 == 0) atomicAdd(&Sbuf[bh * 64 + ci * 16 + lm], s2);
        }
    }
    float* dst = part2 + ((size_t)ns * 256 + bh) * 4096 + (wd + lm) * 64 + we;
#pragma unroll
    for (int nt = 0; nt < 2; nt++)
        *(f32x4*)(dst + nt * 16 + q4 * 4) = acc2[nt];
}

// ---------- fused q GEMM + per-head softmax + PV (BK=64, swizzled LDS) ----------
// A = normed, BT = wqkvT q-rows. Block: 128 rows x 128 cols = 2 complete heads.
// BK=64: As/Bs [128][64] (32 KB, under the 51.2 KB union -> occupancy unchanged),
// halves barrier count. Bank-conflict fix per rule #21: linear gload_lds dest +
// inverse-swizzled GLOBAL source col (chunk (t&7)^((t>>3)&7)) + swizzled read
// (chunk (ki*4+q4)^(row&7)) -> 2-way max (free).
__global__ __launch_bounds__(256) void gemm_qattn(const _Float16* __restrict__ A,
                                                  const _Float16* __restrict__ BT,
                                                  const float* __restrict__ part,
                                                  const float* __restrict__ Sbuf,
                                                  _Float16* __restrict__ attn) {
    // smem: As/Bs (32 KB) during K-loop; then qn[128][132] (33792 B) + csT[2][64][68] (17408 B)
    __shared__ __attribute__((aligned(16))) char smem[33792 + 17408];
    _Float16* As  = (_Float16*)smem;             // [128][64] 16 KB
    _Float16* Bs  = (_Float16*)(smem + 16384);   // [128][64] 16 KB
    _Float16* qn  = (_Float16*)smem;             // [128][132]
    _Float16* csT = (_Float16*)(smem + 33792);   // [2][64][68]
    int t = threadIdx.x, w = t >> 6, lane = t & 63;
    int lm = lane & 15, q4 = lane >> 4;
    int m0 = blockIdx.y * 128, n0 = blockIdx.x * 128;
    int wm = (w & 1) * 64, wn = (w >> 1) * 64;
    f32x4 acc[4][4];
#pragma unroll
    for (int i = 0; i < 4; i++)
#pragma unroll
        for (int j = 0; j < 4; j++) acc[i][j] = (f32x4){0.f, 0.f, 0.f, 0.f};

    // staging: thread t -> row t>>3 (+32 per call), LDS chunk t&7; source col chunk
    // pre-swizzled by row&7 so swizzled READS see conflict-free banks (rule #21).
    int sr8 = t >> 3;
    int swc = (((t & 7) ^ ((t >> 3) & 7)) * 8);
    const _Float16* Ag = A + (size_t)(m0 + sr8) * 512 + swc;
    const _Float16* Bg = BT + (size_t)(n0 + sr8) * 512 + swc;

    for (int k0 = 0; k0 < 512; k0 += 64) {
#pragma unroll
        for (int j = 0; j < 4; j++) {
            gload16(Ag + (size_t)j * 32 * 512 + k0, As + j * 2048 + w * 512);
            gload16(Bg + (size_t)j * 32 * 512 + k0, Bs + j * 2048 + w * 512);
        }
        __syncthreads();
#pragma unroll
        for (int ki = 0; ki < 2; ki++) {
            h8 af[4], bf[4];
#pragma unroll
            for (int i = 0; i < 4; i++) {
                int ra = wm + i * 16 + lm, rb = wn + i * 16 + lm;
                af[i] = *(const h8*)(As + ra * 64 + (((ki * 4 + q4) ^ (ra & 7)) * 8));
                bf[i] = *(const h8*)(Bs + rb * 64 + (((ki * 4 + q4) ^ (rb & 7)) * 8));
            }
#pragma unroll
            for (int mi = 0; mi < 4; mi++)
#pragma unroll
                for (int ni = 0; ni < 4; ni++)
                    acc[mi][ni] = __builtin_amdgcn_mfma_f32_16x16x32_f16(bf[ni], af[mi], acc[mi][ni], 0, 0, 0);
        }
        __syncthreads();
    }
    // per-row softmax over this wave's head (64 cols): exp in-place, row sums via shfl over q4
    float rws[4];
#pragma unroll
    for (int mi = 0; mi < 4; mi++) {
        float s = 0.f;
#pragma unroll
        for (int ni = 0; ni < 4; ni++) {
            f32x4 e;
#pragma unroll
            for (int r = 0; r < 4; r++) {
                e[r] = __expf(clampf(acc[mi][ni][r], -30.f, 30.f));
                s += e[r];
            }
            acc[mi][ni] = e;
        }
        s += __shfl_xor(s, 16);
        s += __shfl_xor(s, 32);
        rws[mi] = 1.f / (s * 8.f);           // softmax / sqrt(64)
    }
    // write qn tile (f16) to LDS (overlays As/Bs; safe after final K-loop barrier)
#pragma unroll
    for (int mi = 0; mi < 4; mi++) {
        int row = wm + mi * 16 + lm;
        float r = rws[mi];
#pragma unroll
        for (int ni = 0; ni < 4; ni++) {
            int col0 = wn + ni * 16 + q4 * 4;
            h4v o;
#pragma unroll
            for (int j = 0; j < 4; j++) o[j] = (_Float16)(acc[mi][ni][j] * r);
            *(h4v*)(qn + row * 132 + col0) = o;
        }
    }
    // stage csT[hh][e][d] = (part2[0]+part2[1])[bh][d][e] * invS[d]  (f16, B^T layout)
    int bl = m0 >> 10;
    int head0 = n0 >> 6;
#pragma unroll
    for (int hh2 = 0; hh2 < 2; hh2++) {
        int bh = bl * 8 + head0 + hh2;
        const f32x4* p0 = (const f32x4*)(part + (size_t)bh * 4096);
        const f32x4* p1 = (const f32x4*)(part + (size_t)(256 + bh) * 4096);
        for (int i = t; i < 1024; i += 256) {
            f32x4 v = p0[i] + p1[i];
            int d = i >> 4, e0 = (i & 15) * 4;
            float is = 1.f / Sbuf[bh * 64 + d];
#pragma unroll
            for (int j = 0; j < 4; j++)
                csT[hh2 * 64 * 68 + (e0 + j) * 68 + d] = (_Float16)(v[j] * is);
        }
    }
    __syncthreads();
    // PV: per wave: rows wm..+63 of its head hh = w>>1, e-cols wn&63 (== output cols)
    int hh = w >> 1;
    f32x4 acc2[4][4];
#pragma unroll
    for (int i = 0; i < 4; i++)
#pragma unroll
        for (int j = 0; j < 4; j++) acc2[i][j] = (f32x4){0.f, 0.f, 0.f, 0.f};
#pragma unroll
    for (int kc = 0; kc < 2; kc++) {
        h8 af[4], bf[4];
#pragma unroll
        for (int mi = 0; mi < 4; mi++) {
            const _Float16* p = qn + (wm + mi * 16 + lm) * 132 + hh * 64 + kc * 32 + q4 * 8;
            h4v lo = *(const h4v*)p;
            h4v hi = *(const h4v*)(p + 4);
            h8 a;
#pragma unroll
            for (int j = 0; j < 4; j++) { a[j] = lo[j]; a[4 + j] = hi[j]; }
            af[mi] = a;
        }
#pragma unroll
        for (int ni = 0; ni < 4; ni++) {
            const _Float16* p = csT + hh * 64 * 68 + (ni * 16 + lm) * 68 + kc * 32 + q4 * 8;
            h4v lo = *(const h4v*)p;
            h4v hi = *(const h4v*)(p + 4);
            h8 b;
#pragma unroll
            for (int j = 0; j < 4; j++) { b[j] = lo[j]; b[4 + j] = hi[j]; }
            bf[ni] = b;
        }
#pragma unroll
        for (int mi = 0; mi < 4; mi++)
#pragma unroll
            for (int ni = 0; ni < 4; ni++)
                acc2[mi][ni] = __builtin_amdgcn_mfma_f32_16x16x32_f16(bf[ni], af[mi], acc2[mi][ni], 0, 0, 0);
    }
#pragma unroll
    for (int mi = 0; mi < 4; mi++) {
        int row = m0 + wm + mi * 16 + lm;
#pragma unroll
        for (int ni = 0; ni < 4; ni++) {
            int col0 = n0 + wn + ni * 16 + q4 * 4;   // == h*64 + e directly
            h4v o;
#pragma unroll
            for (int r = 0; r < 4; r++) o[r] = (_Float16)acc2[mi][ni][r];
            *(h4v*)(attn + (size_t)row * 512 + col0) = o;
        }
    }
}

// ---------- fused projection GEMM + bias + LN2 + residual (64-row blocks) ----------
// out[m0+row][:] = LN( attn[row] . woutT^T / 1024 + b_out ) * ln2_scale + x[row]
// 512 threads = 8 waves, each wave -> 64-col slice; 64 rows/block (full rows -> LN in-block).
__global__ __launch_bounds__(512) void gemm_projln2(const _Float16* __restrict__ A,
                                                    const _Float16* __restrict__ BT,
                                                    const float* __restrict__ bias,
                                                    const float* __restrict__ x,
                                                    const float* __restrict__ scale,
                                                    float* __restrict__ out) {
    __shared__ __attribute__((aligned(16))) _Float16 As[64 * 32];    //  4 KB
    __shared__ __attribute__((aligned(16))) _Float16 Bs[512 * 32];   // 32 KB
    __shared__ float rs_sum[64][8];                                  //  2 KB
    __shared__ float rs_ssq[64][8];                                  //  2 KB
    int t = threadIdx.x, w = t >> 6, lane = t & 63;
    int lm = lane & 15, q4 = lane >> 4;
    int m0 = blockIdx.x * 64;
    f32x4 acc[4][4];   // [mi][ni]: row = m0+mi*16+lm, col = w*64+ni*16+q4*4+r
#pragma unroll
    for (int i = 0; i < 4; i++)
#pragma unroll
        for (int j = 0; j < 4; j++) acc[i][j] = (f32x4){0.f, 0.f, 0.f, 0.f};

    int sr = t >> 2, sc = (t & 3) * 8;     // B staging: rows 0..127 per call
    const _Float16* Ag = A + (size_t)(m0 + (w & 3) * 16 + (lane >> 2)) * 512 + (lane & 3) * 8;
    const _Float16* Bg = BT + (size_t)sr * 512 + sc;
    _Float16* AsW = As + (w & 3) * 512;    // wave-uniform (lane*16B implied)

    for (int k0 = 0; k0 < 512; k0 += 32) {
        if (w < 4) gload16(Ag + k0, AsW);  // waves 0-3 stage 16 rows each
#pragma unroll
        for (int j = 0; j < 4; j++)
            gload16(Bg + (size_t)j * 128 * 512 + k0, Bs + j * 4096 + w * 512);
        __syncthreads();
        h8 af[4], bf[4];
#pragma unroll
        for (int i = 0; i < 4; i++) af[i] = *(const h8*)(As + (i * 16 + lm) * 32 + q4 * 8);
#pragma unroll
        for (int i = 0; i < 4; i++) bf[i] = *(const h8*)(Bs + (w * 64 + i * 16 + lm) * 32 + q4 * 8);
#pragma unroll
        for (int mi = 0; mi < 4; mi++)
#pragma unroll
            for (int ni = 0; ni < 4; ni++)
                acc[mi][ni] = __builtin_amdgcn_mfma_f32_16x16x32_f16(bf[ni], af[mi], acc[mi][ni], 0, 0, 0);
        __syncthreads();
    }
    // scale + bias; per-(row,wave) partials over this wave's 64 cols
    const float os = 1.f / 1024.f;
#pragma unroll
    for (int mi = 0; mi < 4; mi++) {
        float s = 0.f, ss = 0.f;
#pragma unroll
        for (int ni = 0; ni < 4; ni++) {
            float4 b4 = *(const float4*)(bias + w * 64 + ni * 16 + q4 * 4);
            const float* bp = &b4.x;
#pragma unroll
            for (int r = 0; r < 4; r++) {
                float v = acc[mi][ni][r] * os + bp[r];
                acc[mi][ni][r] = v;
                s += v; ss += v * v;
            }
        }
        s  += __shfl_xor(s, 16);  s  += __shfl_xor(s, 32);
        ss += __shfl_xor(ss, 16); ss += __shfl_xor(ss, 32);
        if (q4 == 0) {
            rs_sum[mi * 16 + lm][w] = s;
            rs_ssq[mi * 16 + lm][w] = ss;
        }
    }
    __syncthreads();
#pragma unroll
    for (int mi = 0; mi < 4; mi++) {
        int r64 = mi * 16 + lm;
        float s = 0.f, ss = 0.f;
#pragma unroll
        for (int k = 0; k < 8; k++) { s += rs_sum[r64][k]; ss += rs_ssq[r64][k]; }
        float mean = s * (1.f / 512.f);
        float var  = ss * (1.f / 512.f) - mean * mean;
        float rstd = rsqrtf(fmaxf(var, 0.f) + 1e-5f);
        int row = m0 + r64;
#pragma unroll
        for (int ni = 0; ni < 4; ni++) {
            int col0 = w * 64 + ni * 16 + q4 * 4;
            float4 sc4 = *(const float4*)(scale + col0);
            float4 x4  = *(const float4*)(x + (size_t)row * 512 + col0);
            const float* scp = &sc4.x; const float* xp = &x4.x;
            float4 o;
            float* op = &o.x;
#pragma unroll
            for (int r = 0; r < 4; r++)
                op[r] = (acc[mi][ni][r] - mean) * rstd * scp[r] + xp[r];
            *(float4*)(out + (size_t)row * 512 + col0) = o;
        }
    }
}

// ---------- launch ----------
extern "C" void kernel_launch(void* const* d_in, const int* in_sizes, int n_in,
                              void* d_out, int out_size, void* d_ws, size_t ws_size,
                              hipStream_t stream) {
    const float* x    = (const float*)d_in[0];
    const float* ln1s = (const float*)d_in[1];
    const float* wqkv = (const float*)d_in[2];
    const float* wout = (const float*)d_in[3];
    const float* bout = (const float*)d_in[4];
    const float* ln2s = (const float*)d_in[5];
    float* out = (float*)d_out;

    char* ws = (char*)d_ws;
    // ws layout (unchanged footprint):
    _Float16* wqkvT  = (_Float16*)(ws);                     // 1,572,864
    _Float16* woutT  = (_Float16*)(ws + 1572864);           //   524,288
    float*    Sbuf   = (float*)(ws + 6291456);              // [256][64] f32 : 64 KiB
    _Float16* normed = (_Float16*)(ws + 6356992);           // [32768][512] f16 : 32 MiB
    _Float16* attnF  = (_Float16*)(ws + 39911424);          // [32768][512] f16 : 32 MiB
    // d_out (64 MiB) is scratch until gemm_projln2: part2 dead after qattn.
    float* part2 = (float*)d_out;                           // [2][256][64][64] f32 : 8 MiB

    transpose_f2h<<<dim3(48, 16), 256, 0, stream>>>(wqkv, wqkvT, 512, 1536);
    transpose_f2h<<<dim3(16, 16), 256, 0, stream>>>(wout, woutT, 512, 512);
    ln1_kernel<<<8192, 256, 0, stream>>>(x, ln1s, normed);
    hipMemsetAsync(Sbuf, 0, 65536, stream);

    // kv GEMM + exp + S + ctx fused (no ekT/vT materialization) — R8 proven config
    gemm_kvctx<<<dim3(2, 256), 512, 0, stream>>>(normed, wqkvT + 512 * 512, part2, Sbuf);
    // q = normed . w_qkv[:, 0:512] with fused softmax + PV (all batches)
    gemm_qattn<<<dim3(4, 256), 256, 0, stream>>>(normed, wqkvT, part2, Sbuf, attnF);
    // out = LN(attn . w_out^T / 1024 + b_out) * ln2_scale + x
    gemm_projln2<<<512, 512, 0, stream>>>(attnF, woutT, bout, x, ln2s, out);
}